// Round 5
// baseline (497.086 us; speedup 1.0000x reference)
//
#include <hip/hip_runtime.h>
#include <hip/hip_cooperative_groups.h>

namespace cg = cooperative_groups;

// Problem: B=2, DIM=512, NUM_HEADS=1, tokens TOK=256 (16x16 window, w=1).
// SINGLE cooperative kernel, 512 blocks x 256 threads (2 blocks/CU), 4 phases:
//   P0: prep jobs 0..131071 (qkv_w + x -> bf16 hi/lo frag-tiled planes)
//   P1: blocks <384: qkv GEMM (bf16 split-3 MFMA, 4-wave intra-block K-split)
//       blocks >=384: prep jobs 131072..163839 (proj_w planes) — overlapped
//   P2: fused per-channel attention (all 512 blocks); epilogue writes aout as
//       hi/lo frag-tiled planes (proj's B operand)
//   P3: blocks <256: proj GEMM -> out + bias
// grid.sync() between phases (cooperative launch guarantees co-residency).
//
// Frag-tiled layout for an MFMA operand (A: [M][K] rows=m; B: logical [K][N]
// consumed as [n][k]):  idx(r, k) = ((r/16)*(K/8) + k/8)*128 + (r%16)*8 + (k%8)
// A wave's fragment load (lr=lane&15 row, lg=lane>>4 k-chunk) is 64 lanes x 16B
// = one contiguous 1 KiB block -> perfect coalesce, L2-resident.
//
// ws layout: ushort planes first, then fp32 qkv buffer.
//   WqAh 0        WqAl 786432    (qkv_w planes, 1536x512)
//   XBh  1572864  XBl  1835008   (x planes,     2x[256n][512k])
//   WpAh 2097152  WpAl 2359296   (proj_w planes, 512x512)
//   AoBh 2621440  AoBl 2883584   (aout planes,  2x[256n][512k])
//   qkvf32 at float offset 1572864 (byte 6291456): [2][1536][256] fp32
// total 9.4 MB of d_ws.

#define TOK    256
#define KDIM   512
#define K8     64                   // KDIM/8
#define LOG2E  1.4426950408889634f
#define SCALE  0.04419417382415922f // 512^{-1/2}

#define OFF_WQAH 0
#define OFF_WQAL 786432
#define OFF_XBH  1572864
#define OFF_XBL  1835008
#define OFF_WPAH 2097152
#define OFF_WPAL 2359296
#define OFF_AOBH 2621440
#define OFF_AOBL 2883584
#define OFF_QKVF 1572864            // float offset

#define EXP2(x) __builtin_amdgcn_exp2f(x)

typedef __attribute__((ext_vector_type(8))) short short8_t;  // 8 bf16 (4 VGPR)
typedef __attribute__((ext_vector_type(4))) float f32x4;     // MFMA acc

// round-to-nearest-even fp32 -> bf16 bits
__device__ __forceinline__ unsigned short f2bf(float x) {
    unsigned int u = __float_as_uint(x);
    u += 0x7fffu + ((u >> 16) & 1u);
    return (unsigned short)(u >> 16);
}
__device__ __forceinline__ float bf2f(unsigned short h) {
    return __uint_as_float((unsigned int)h << 16);
}

__device__ __forceinline__ void cvt8(const float* v, unsigned short* hq,
                                     unsigned short* lq) {
#pragma unroll
    for (int j = 0; j < 8; ++j) {
        const unsigned short h = f2bf(v[j]);
        hq[j] = h;
        lq[j] = f2bf(v[j] - bf2f(h));
    }
}

// Shared-memory union. Member order keeps every float4-accessed array at a
// 16B-aligned offset: ks 0, vs 2048, lpart 4096, apart 6144, tab2 8192,
// brow 8448 (float2-accessed, 8B-aligned). Total 40440 B.
struct AttnSmem {
    float ks[2][TOK];
    float vs[2][TOK];
    float lpart[2][TOK];
    float apart[2][TOK];
    float tab2[64];
    float brow[31][258];
};
// gemm reduce view: float red[4][32][68] = 34816 B (aliases the same buffer)

// ---------------------------------------------------------------------------
// prep job j (j < 163840): convert one 8-wide k-chunk to hi/lo planes.
//   [0,98304):        qkv_w [1536][512] -> WqAh/WqAl (A-frag layout)
//   [98304,131072):   x [2][512][256]   -> XBh/XBl   (B-frag layout, n=tok)
//   [131072,163840):  proj_w [512][512] -> WpAh/WpAl
// ---------------------------------------------------------------------------
__device__ __forceinline__ void do_prep(int id, const float* __restrict__ qkv_w,
                                        const float* __restrict__ x,
                                        const float* __restrict__ proj_w,
                                        unsigned short* __restrict__ U)
{
    alignas(16) unsigned short hq[8], lq[8];
    float v[8];

    if (id < 98304) {                       // qkv_w
        const int m = id >> 6, kc = id & 63;
        const float* s = qkv_w + (size_t)m * KDIM + kc * 8;
#pragma unroll
        for (int j = 0; j < 8; ++j) v[j] = s[j];
        cvt8(v, hq, lq);
        const size_t o = ((size_t)(m >> 4) * K8 + kc) * 128 + (size_t)(m & 15) * 8;
        *(uint4*)(U + OFF_WQAH + o) = *(const uint4*)hq;
        *(uint4*)(U + OFF_WQAL + o) = *(const uint4*)lq;
    } else if (id < 131072) {               // x (transpose k<->n into B-frag)
        const int rid = id - 98304;
        const int n = rid & 255, kc = (rid >> 8) & 63, b = rid >> 14;
        const float* s = x + ((size_t)b * KDIM + kc * 8) * TOK + n;
#pragma unroll
        for (int j = 0; j < 8; ++j) v[j] = s[(size_t)j * TOK];
        cvt8(v, hq, lq);
        const size_t o = (((size_t)b * 16 + (n >> 4)) * K8 + kc) * 128
                         + (size_t)(n & 15) * 8;
        *(uint4*)(U + OFF_XBH + o) = *(const uint4*)hq;
        *(uint4*)(U + OFF_XBL + o) = *(const uint4*)lq;
    } else {                                // proj_w (id < 163840)
        const int rid = id - 131072;
        const int m = rid >> 6, kc = rid & 63;
        const float* s = proj_w + (size_t)m * KDIM + kc * 8;
#pragma unroll
        for (int j = 0; j < 8; ++j) v[j] = s[j];
        cvt8(v, hq, lq);
        const size_t o = ((size_t)(m >> 4) * K8 + kc) * 128 + (size_t)(m & 15) * 8;
        *(uint4*)(U + OFF_WPAH + o) = *(const uint4*)hq;
        *(uint4*)(U + OFF_WPAL + o) = *(const uint4*)lq;
    }
}

// ---------------------------------------------------------------------------
// Fragment GEMM phase: block tile (MT*16) m x 64 n; wave w owns K-slice
// [128w, 128w+128) (4 K-steps of 32, ping-pong register prefetch); partials
// summed through padded LDS (stride 68 -> conflict-free) and stored.
// ---------------------------------------------------------------------------
template<int MT, bool BIAS>
__device__ __forceinline__ void gemm_phase(
    const int bx, const int by, const int bz, const int t,
    const unsigned short* __restrict__ Ah, const unsigned short* __restrict__ Al,
    const unsigned short* __restrict__ Bh, const unsigned short* __restrict__ Bl,
    const float* __restrict__ bias, float* __restrict__ Cout, const int Mtot,
    float* __restrict__ red)
{
#define REDX(W, R, C) red[((W) * (MT * 16) + (R)) * 68 + (C)]
    const int w    = t >> 6;         // wave id = K-slice
    const int lane = t & 63;
    const int lr   = lane & 15;      // frag row (A) / col (B) / col (D)
    const int lg   = lane >> 4;      // k-chunk group / D row-quad
    const int mt0  = bx * MT;
    const int nt0  = by * 4;         // 16-col tile units
    const int b    = bz;

    f32x4 acc[MT][4];
#pragma unroll
    for (int mi = 0; mi < MT; ++mi)
#pragma unroll
        for (int ni = 0; ni < 4; ++ni)
            acc[mi][ni] = (f32x4){0.f, 0.f, 0.f, 0.f};

    short8_t ah[2][MT], al[2][MT], bh[2][4], bl[2][4];

#define LDF(S, P) do {                                                        \
        const int kc_ = w * 16 + (S) * 4 + lg;                                \
        _Pragma("unroll")                                                     \
        for (int mi = 0; mi < MT; ++mi) {                                     \
            const size_t o_ = ((size_t)(mt0 + mi) * K8 + kc_) * 128           \
                              + (size_t)lr * 8;                               \
            ah[P][mi] = *(const short8_t*)(Ah + o_);                          \
            al[P][mi] = *(const short8_t*)(Al + o_);                          \
        }                                                                     \
        _Pragma("unroll")                                                     \
        for (int ni = 0; ni < 4; ++ni) {                                      \
            const size_t o_ = (((size_t)b * 16 + nt0 + ni) * K8 + kc_) * 128  \
                              + (size_t)lr * 8;                               \
            bh[P][ni] = *(const short8_t*)(Bh + o_);                          \
            bl[P][ni] = *(const short8_t*)(Bl + o_);                          \
        }                                                                     \
    } while (0)

    LDF(0, 0);
#pragma unroll
    for (int s = 0; s < 4; ++s) {            // 4 K-steps of 32 per wave
        const int p = s & 1;
        if (s + 1 < 4) LDF(s + 1, p ^ 1);    // prefetch next step's frags
#pragma unroll
        for (int mi = 0; mi < MT; ++mi)
#pragma unroll
            for (int ni = 0; ni < 4; ++ni) {
                acc[mi][ni] = __builtin_amdgcn_mfma_f32_16x16x32_bf16(
                    ah[p][mi], bh[p][ni], acc[mi][ni], 0, 0, 0);
                acc[mi][ni] = __builtin_amdgcn_mfma_f32_16x16x32_bf16(
                    al[p][mi], bh[p][ni], acc[mi][ni], 0, 0, 0);
                acc[mi][ni] = __builtin_amdgcn_mfma_f32_16x16x32_bf16(
                    ah[p][mi], bl[p][ni], acc[mi][ni], 0, 0, 0);
            }
    }
#undef LDF

    // cross-wave reduce: D frag (col=lr, row=lg*4+r) -> LDS -> sum -> global
#pragma unroll
    for (int mi = 0; mi < MT; ++mi)
#pragma unroll
        for (int ni = 0; ni < 4; ++ni)
#pragma unroll
            for (int r = 0; r < 4; ++r)
                REDX(w, mi * 16 + lg * 4 + r, ni * 16 + lr) = acc[mi][ni][r];
    __syncthreads();

#pragma unroll
    for (int it = 0; it < MT; ++it) {
        const int rr = it * 16 + (t >> 4);   // local row 0..MT*16-1
        const int cc = (t & 15) * 4;         // local col (float4)
        float4 v0 = *(const float4*)&REDX(0, rr, cc);
        const float4 v1 = *(const float4*)&REDX(1, rr, cc);
        const float4 v2 = *(const float4*)&REDX(2, rr, cc);
        const float4 v3 = *(const float4*)&REDX(3, rr, cc);
        v0.x += v1.x + v2.x + v3.x;
        v0.y += v1.y + v2.y + v3.y;
        v0.z += v1.z + v2.z + v3.z;
        v0.w += v1.w + v2.w + v3.w;
        const int grow = mt0 * 16 + rr;
        if (BIAS) {
            const float pb = bias[grow];
            v0.x += pb; v0.y += pb; v0.z += pb; v0.w += pb;
        }
        *(float4*)(Cout + ((size_t)b * Mtot + grow) * TOK + nt0 * 16 + cc) = v0;
    }
#undef REDX
}

// ---------------------------------------------------------------------------
// Fused per-channel attention phase. Block handles (b = bid>>8, d0 = 2*(bid&255)).
// Reads the unsplit fp32 qkv buffer [b][1536][256]; adds qkv bias inline.
// bias[h,g] = tab[r(h)-r(g)+30], r(h)=(h>>4)+(h&15): 61 distinct values,
// replicated into brow[31][258] (2-bank step, conflict-free float2 reads).
// Scores bounded (~1.1) -> no max-subtraction; g-half partials merge additively.
// Epilogue writes aout as hi/lo bf16 planes in proj's B-frag layout.
// ---------------------------------------------------------------------------
__device__ __forceinline__ void attn_phase(
    const int bid, const int t,
    const float* __restrict__ qkvf, const float* __restrict__ qkv_b,
    const float* __restrict__ rpb,
    unsigned short* __restrict__ aoh, unsigned short* __restrict__ aol,
    AttnSmem& S)
{
    const int b  = bid >> 8;
    const int d0 = (bid & 255) * 2;
    const float* q0 = qkvf + (size_t)b * (1536 * TOK);

    // phase 0: bias table (61 values)
    if (t < 61) {
        const int rel = t - 30;
        S.tab2[t] = rpb[rel < 0 ? rel + 961 : rel] * LOG2E;
    }
    // phase 1: stage k and v rows for the 2 channels (+qkv bias)
    {
        const int sel = t >> 7;          // 0: k, 1: v
        const int row = (t >> 6) & 1;    // dl
        const int g4  = (t & 63) * 4;
        const int o   = (sel ? 1024 : 512) + d0 + row;
        const float bb = qkv_b[o];
        float4 v = *(const float4*)(q0 + (size_t)o * TOK + g4);
        v.x += bb; v.y += bb; v.z += bb; v.w += bb;
        if (sel == 0) {
            const float s = SCALE * LOG2E;
            v.x *= s; v.y *= s; v.z *= s; v.w *= s;
            *(float4*)&S.ks[row][g4] = v;
        } else {
            *(float4*)&S.vs[row][g4] = v;
        }
    }
    __syncthreads();
    // phase 2: replicate bias into 31 rows x 256 g
    {
        const int rg = ((t >> 4) & 15) + (t & 15);
#pragma unroll 1
        for (int it = 0; it < 31; ++it)
            S.brow[it][t] = S.tab2[it - rg + 30];
    }
    __syncthreads();

    // phase 3: main loop
    const int w   = t >> 6;
    const int dl  = w & 1;
    const int gh  = w >> 1;
    const int hl  = t & 63;
    const int qi  = ((hl & 15) << 2) | (hl >> 4);  // bit-swizzled h-quad index
    const int h0  = qi * 4;
    const int rh0 = (qi >> 2) + 4 * (qi & 3);      // r(h0); r(h0+r)=rh0+r

    float q[4];
    {
        const float bb = qkv_b[d0 + dl];
        const float4 x4 = *(const float4*)(q0 + (size_t)(d0 + dl) * TOK + h0);
        q[0] = x4.x + bb; q[1] = x4.y + bb; q[2] = x4.z + bb; q[3] = x4.w + bb;
    }

    float l[4]  = {0.f, 0.f, 0.f, 0.f};
    float am[4] = {0.f, 0.f, 0.f, 0.f};

    const int pbeg = gh * 128;
#pragma unroll 2
    for (int p = pbeg; p < pbeg + 128; p += 4) {
        const float4 k4 = *(const float4*)&S.ks[dl][p];  // wave-uniform (bcast)
        const float4 v4 = *(const float4*)&S.vs[dl][p];
#pragma unroll
        for (int r = 0; r < 4; ++r) {
            const float2 b01 = *(const float2*)&S.brow[rh0 + r][p];
            const float2 b23 = *(const float2*)&S.brow[rh0 + r][p + 2];
            float e;
            e = EXP2(fmaf(q[r], k4.x, b01.x)); l[r] += e; am[r] = fmaf(e, v4.x, am[r]);
            e = EXP2(fmaf(q[r], k4.y, b01.y)); l[r] += e; am[r] = fmaf(e, v4.y, am[r]);
            e = EXP2(fmaf(q[r], k4.z, b23.x)); l[r] += e; am[r] = fmaf(e, v4.z, am[r]);
            e = EXP2(fmaf(q[r], k4.w, b23.y)); l[r] += e; am[r] = fmaf(e, v4.w, am[r]);
        }
    }

    // phase 4: merge g-halves, normalize, store as hi/lo planes (B-frag layout)
    if (gh == 1) {
        *(float4*)&S.lpart[dl][h0] = make_float4(l[0], l[1], l[2], l[3]);
        *(float4*)&S.apart[dl][h0] = make_float4(am[0], am[1], am[2], am[3]);
    }
    __syncthreads();
    if (gh == 0) {
        const float4 lo = *(const float4*)&S.lpart[dl][h0];
        const float4 ao = *(const float4*)&S.apart[dl][h0];
        float vals[4];
        vals[0] = (am[0] + ao.x) / (l[0] + lo.x);
        vals[1] = (am[1] + ao.y) / (l[1] + lo.y);
        vals[2] = (am[2] + ao.z) / (l[2] + lo.z);
        vals[3] = (am[3] + ao.w) / (l[3] + lo.w);
        const int d = d0 + dl;
        const size_t ob = (((size_t)b * 16 + (h0 >> 4)) * K8 + (d >> 3)) * 128
                          + (size_t)(h0 & 15) * 8 + (d & 7);
#pragma unroll
        for (int r = 0; r < 4; ++r) {
            const unsigned short hh = f2bf(vals[r]);
            aoh[ob + (size_t)r * 8] = hh;
            aol[ob + (size_t)r * 8] = f2bf(vals[r] - bf2f(hh));
        }
    }
}

// ---------------------------------------------------------------------------
// The fused cooperative kernel: 512 blocks x 256 threads, 2 blocks/CU.
// ---------------------------------------------------------------------------
__global__ __launch_bounds__(256, 2)
void fused(const float* __restrict__ x, const float* __restrict__ qkv_w,
           const float* __restrict__ qkv_b, const float* __restrict__ proj_w,
           const float* __restrict__ proj_b, const float* __restrict__ rpb,
           float* __restrict__ out, unsigned short* __restrict__ U)
{
    __shared__ alignas(16) float4 smem4[2528];   // 40448 B union
    AttnSmem& S = *reinterpret_cast<AttnSmem*>(smem4);
    float* red = reinterpret_cast<float*>(smem4);

    const int t   = threadIdx.x;
    const int bid = blockIdx.x;
    cg::grid_group grid = cg::this_grid();
    float* qkvf = reinterpret_cast<float*>(U) + OFF_QKVF;

    // P0: prep qkv_w + x planes (exactly 1 job/thread, 131072 jobs)
    do_prep(bid * 256 + t, qkv_w, x, proj_w, U);
    __threadfence();
    grid.sync();

    // P1: qkv GEMM on 384 blocks; the 128 idle blocks prep proj_w (32768 jobs)
    if (bid < 384) {
        const int bx = bid % 48, rem = bid / 48;
        gemm_phase<2, false>(bx, rem & 3, rem >> 2, t,
                             U + OFF_WQAH, U + OFF_WQAL, U + OFF_XBH, U + OFF_XBL,
                             nullptr, qkvf, 1536, red);
    } else {
        do_prep(131072 + (bid - 384) * 256 + t, qkv_w, x, proj_w, U);
    }
    __threadfence();
    grid.sync();

    // P2: attention (all 512 blocks)
    attn_phase(bid, t, qkvf, qkv_b, rpb, U + OFF_AOBH, U + OFF_AOBL, S);
    __threadfence();
    grid.sync();

    // P3: proj GEMM -> out (+bias) on 256 blocks
    if (bid < 256) {
        const int bx = bid % 32, rem = bid / 32;
        gemm_phase<1, true>(bx, rem & 3, rem >> 2, t,
                            U + OFF_WPAH, U + OFF_WPAL, U + OFF_AOBH, U + OFF_AOBL,
                            proj_b, out, 512, red);
    }
}

// ---------------------------------------------------------------------------
extern "C" void kernel_launch(void* const* d_in, const int* in_sizes, int n_in,
                              void* d_out, int out_size, void* d_ws, size_t ws_size,
                              hipStream_t stream)
{
    const float* x      = (const float*)d_in[0];   // [2][512][256]
    const float* qkv_w  = (const float*)d_in[1];   // [1536][512]
    const float* qkv_b  = (const float*)d_in[2];   // [1536]
    const float* proj_w = (const float*)d_in[3];   // [512][512]
    const float* proj_b = (const float*)d_in[4];   // [512]
    const float* rpb    = (const float*)d_in[5];   // [961]
    float* out          = (float*)d_out;           // [2][512][256]
    unsigned short* U   = (unsigned short*)d_ws;

    void* args[8] = { (void*)&x, (void*)&qkv_w, (void*)&qkv_b, (void*)&proj_w,
                      (void*)&proj_b, (void*)&rpb, (void*)&out, (void*)&U };
    hipLaunchCooperativeKernel(fused, dim3(512), dim3(256), args, 0u, stream);
}

// Round 6
// 99.808 us; speedup vs baseline: 4.9804x; 4.9804x over previous
//
#include <hip/hip_runtime.h>

// Problem: B=2, DIM=512, NUM_HEADS=1, tokens TOK=256 (16x16 window, w=1).
// Pipeline (4 kernels) — reverted to the verified R4 structure after the
// cooperative mega-kernel (R5) showed grid.sync() costs ~127 us each on
// gfx950 (3 syncs = ~380 us of stall vs ~6 us of launch gaps saved):
//   prep      : convert qkv_w, x, proj_w -> bf16 hi/lo planes, MFMA-frag-tiled
//   gemm_frag : bf16 split-3 MFMA GEMM, 256-thr blocks, 4-wave INTRA-BLOCK
//               K-split + LDS cross-wave reduce (qkv -> fp32; proj -> out+bias)
//   attn_f32  : fused per-channel attention; epilogue writes aout as frag-tiled
//               hi/lo planes (proj's B operand)
//
// Frag-tiled layout for an MFMA operand (A: [M][K] rows=m; B: logical [K][N]
// consumed as [n][k]):  idx(r, k) = ((r/16)*(K/8) + k/8)*128 + (r%16)*8 + (k%8)
// A wave's fragment load (lr=lane&15 row, lg=lane>>4 k-chunk) is 64 lanes x 16B
// = one contiguous 1 KiB block -> perfect coalesce, L2-resident.
//
// ws layout: ushort planes first, then fp32 qkv buffer.
//   WqAh 0        WqAl 786432    (qkv_w planes, 1536x512)
//   XBh  1572864  XBl  1835008   (x planes,     2x[256n][512k])
//   WpAh 2097152  WpAl 2359296   (proj_w planes, 512x512)
//   AoBh 2621440  AoBl 2883584   (aout planes,  2x[256n][512k])
//   qkvf32 at float offset 1572864 (byte 6291456): [2][1536][256] fp32
// total 9.4 MB of d_ws.

#define TOK    256
#define KDIM   512
#define K8     64                   // KDIM/8
#define LOG2E  1.4426950408889634f
#define SCALE  0.04419417382415922f // 512^{-1/2}

#define OFF_WQAH 0
#define OFF_WQAL 786432
#define OFF_XBH  1572864
#define OFF_XBL  1835008
#define OFF_WPAH 2097152
#define OFF_WPAL 2359296
#define OFF_AOBH 2621440
#define OFF_AOBL 2883584
#define OFF_QKVF 1572864            // float offset

#define EXP2(x) __builtin_amdgcn_exp2f(x)

typedef __attribute__((ext_vector_type(8))) short short8_t;  // 8 bf16 (4 VGPR)
typedef __attribute__((ext_vector_type(4))) float f32x4;     // MFMA acc

// round-to-nearest-even fp32 -> bf16 bits
__device__ __forceinline__ unsigned short f2bf(float x) {
    unsigned int u = __float_as_uint(x);
    u += 0x7fffu + ((u >> 16) & 1u);
    return (unsigned short)(u >> 16);
}
__device__ __forceinline__ float bf2f(unsigned short h) {
    return __uint_as_float((unsigned int)h << 16);
}

__device__ __forceinline__ void cvt8(const float* v, unsigned short* hq,
                                     unsigned short* lq) {
#pragma unroll
    for (int j = 0; j < 8; ++j) {
        const unsigned short h = f2bf(v[j]);
        hq[j] = h;
        lq[j] = f2bf(v[j] - bf2f(h));
    }
}

// ---------------------------------------------------------------------------
// prep: one thread per 8-wide k-chunk. 163,840 threads = 640 blocks x 256.
//   job0 [0,98304):      qkv_w [1536][512] -> WqAh/WqAl (A-frag layout)
//   job1 [98304,131072): x [2][512][256]   -> XBh/XBl   (B-frag layout, n=tok)
//   job2 [131072,163840): proj_w [512][512] -> WpAh/WpAl
// ---------------------------------------------------------------------------
__global__ __launch_bounds__(256)
void prep(const float* __restrict__ qkv_w, const float* __restrict__ x,
          const float* __restrict__ proj_w, unsigned short* __restrict__ U)
{
    const int id = blockIdx.x * 256 + threadIdx.x;
    alignas(16) unsigned short hq[8], lq[8];
    float v[8];

    if (id < 98304) {                       // qkv_w
        const int m = id >> 6, kc = id & 63;
        const float* s = qkv_w + (size_t)m * KDIM + kc * 8;
#pragma unroll
        for (int j = 0; j < 8; ++j) v[j] = s[j];
        cvt8(v, hq, lq);
        const size_t o = ((size_t)(m >> 4) * K8 + kc) * 128 + (size_t)(m & 15) * 8;
        *(uint4*)(U + OFF_WQAH + o) = *(const uint4*)hq;
        *(uint4*)(U + OFF_WQAL + o) = *(const uint4*)lq;
    } else if (id < 131072) {               // x (transpose k<->n into B-frag)
        const int rid = id - 98304;
        const int n = rid & 255, kc = (rid >> 8) & 63, b = rid >> 14;
        const float* s = x + ((size_t)b * KDIM + kc * 8) * TOK + n;
#pragma unroll
        for (int j = 0; j < 8; ++j) v[j] = s[(size_t)j * TOK];
        cvt8(v, hq, lq);
        const size_t o = (((size_t)b * 16 + (n >> 4)) * K8 + kc) * 128
                         + (size_t)(n & 15) * 8;
        *(uint4*)(U + OFF_XBH + o) = *(const uint4*)hq;
        *(uint4*)(U + OFF_XBL + o) = *(const uint4*)lq;
    } else if (id < 163840) {               // proj_w
        const int rid = id - 131072;
        const int m = rid >> 6, kc = rid & 63;
        const float* s = proj_w + (size_t)m * KDIM + kc * 8;
#pragma unroll
        for (int j = 0; j < 8; ++j) v[j] = s[j];
        cvt8(v, hq, lq);
        const size_t o = ((size_t)(m >> 4) * K8 + kc) * 128 + (size_t)(m & 15) * 8;
        *(uint4*)(U + OFF_WPAH + o) = *(const uint4*)hq;
        *(uint4*)(U + OFF_WPAL + o) = *(const uint4*)lq;
    }
}

// ---------------------------------------------------------------------------
// Fragment GEMM, 256-thr blocks, intra-block K-split across the 4 waves.
// Block tile: (MT*16) m x 64 n. Wave w accumulates K-slice [128w, 128w+128)
// (4 K-steps of 32, ping-pong register prefetch), then the 4 partial tiles
// are summed through padded LDS (stride 68 -> conflict-free) and stored.
// Grid: (Mtot/(16*MT), TOK/64, 2).  qkv: MT=2 -> 384 blocks; proj: MT=1 -> 256.
// ---------------------------------------------------------------------------
template<int MT, bool BIAS>
__global__ __launch_bounds__(256)
void gemm_frag(const unsigned short* __restrict__ Ah,
               const unsigned short* __restrict__ Al,
               const unsigned short* __restrict__ Bh,
               const unsigned short* __restrict__ Bl,
               const float* __restrict__ bias,
               float* __restrict__ Cout, int Mtot)
{
    alignas(16) __shared__ float red[4][MT * 16][68];

    const int t    = threadIdx.x;
    const int w    = t >> 6;         // wave id = K-slice
    const int lane = t & 63;
    const int lr   = lane & 15;      // frag row (A) / col (B) / col (D)
    const int lg   = lane >> 4;      // k-chunk group / D row-quad
    const int mt0  = blockIdx.x * MT;
    const int nt0  = blockIdx.y * 4; // 16-col tile units
    const int b    = blockIdx.z;

    f32x4 acc[MT][4];
#pragma unroll
    for (int mi = 0; mi < MT; ++mi)
#pragma unroll
        for (int ni = 0; ni < 4; ++ni)
            acc[mi][ni] = (f32x4){0.f, 0.f, 0.f, 0.f};

    short8_t ah[2][MT], al[2][MT], bh[2][4], bl[2][4];

#define LDF(S, P) do {                                                        \
        const int kc_ = w * 16 + (S) * 4 + lg;                                \
        _Pragma("unroll")                                                     \
        for (int mi = 0; mi < MT; ++mi) {                                     \
            const size_t o_ = ((size_t)(mt0 + mi) * K8 + kc_) * 128           \
                              + (size_t)lr * 8;                               \
            ah[P][mi] = *(const short8_t*)(Ah + o_);                          \
            al[P][mi] = *(const short8_t*)(Al + o_);                          \
        }                                                                     \
        _Pragma("unroll")                                                     \
        for (int ni = 0; ni < 4; ++ni) {                                      \
            const size_t o_ = (((size_t)b * 16 + nt0 + ni) * K8 + kc_) * 128  \
                              + (size_t)lr * 8;                               \
            bh[P][ni] = *(const short8_t*)(Bh + o_);                          \
            bl[P][ni] = *(const short8_t*)(Bl + o_);                          \
        }                                                                     \
    } while (0)

    LDF(0, 0);
#pragma unroll
    for (int s = 0; s < 4; ++s) {            // 4 K-steps of 32 per wave
        const int p = s & 1;
        if (s + 1 < 4) LDF(s + 1, p ^ 1);    // prefetch next step's frags
#pragma unroll
        for (int mi = 0; mi < MT; ++mi)
#pragma unroll
            for (int ni = 0; ni < 4; ++ni) {
                acc[mi][ni] = __builtin_amdgcn_mfma_f32_16x16x32_bf16(
                    ah[p][mi], bh[p][ni], acc[mi][ni], 0, 0, 0);
                acc[mi][ni] = __builtin_amdgcn_mfma_f32_16x16x32_bf16(
                    al[p][mi], bh[p][ni], acc[mi][ni], 0, 0, 0);
                acc[mi][ni] = __builtin_amdgcn_mfma_f32_16x16x32_bf16(
                    ah[p][mi], bl[p][ni], acc[mi][ni], 0, 0, 0);
            }
    }
#undef LDF

    // cross-wave reduce: D frag (col=lr, row=lg*4+r) -> LDS -> sum -> global
#pragma unroll
    for (int mi = 0; mi < MT; ++mi)
#pragma unroll
        for (int ni = 0; ni < 4; ++ni)
#pragma unroll
            for (int r = 0; r < 4; ++r)
                red[w][mi * 16 + lg * 4 + r][ni * 16 + lr] = acc[mi][ni][r];
    __syncthreads();

#pragma unroll
    for (int it = 0; it < MT; ++it) {
        const int rr = it * 16 + (t >> 4);   // local row 0..MT*16-1
        const int cc = (t & 15) * 4;         // local col (float4)
        float4 v0 = *(const float4*)&red[0][rr][cc];
        const float4 v1 = *(const float4*)&red[1][rr][cc];
        const float4 v2 = *(const float4*)&red[2][rr][cc];
        const float4 v3 = *(const float4*)&red[3][rr][cc];
        v0.x += v1.x + v2.x + v3.x;
        v0.y += v1.y + v2.y + v3.y;
        v0.z += v1.z + v2.z + v3.z;
        v0.w += v1.w + v2.w + v3.w;
        const int grow = mt0 * 16 + rr;
        if (BIAS) {
            const float pb = bias[grow];
            v0.x += pb; v0.y += pb; v0.z += pb; v0.w += pb;
        }
        // column base = nt0*16 (nt0 in 16-col tile units) + cc
        *(float4*)(Cout + ((size_t)b * Mtot + grow) * TOK + nt0 * 16 + cc) = v0;
    }
}

// ---------------------------------------------------------------------------
// Fused per-channel attention. Block = 256 threads handles (b, d0..d0+1).
// Reads the unsplit fp32 qkv buffer [b][1536][256]; adds qkv bias inline.
// bias[h,g] = tab[r(h)-r(g)+30], r(h)=(h>>4)+(h&15): 61 distinct values,
// replicated into brow[31][258] (2-bank step, conflict-free float2 reads).
// Scores bounded (~1.1) -> no max-subtraction; g-half partials merge additively.
// Epilogue writes aout as hi/lo bf16 planes in proj's B-frag layout.
// ---------------------------------------------------------------------------
__global__ __launch_bounds__(256)
void attn_f32(const float* __restrict__ qkvf, const float* __restrict__ qkv_b,
              const float* __restrict__ rpb,
              unsigned short* __restrict__ aoh, unsigned short* __restrict__ aol)
{
    __shared__ float ks_[2][TOK];      // k * scale * log2e (incl. qkv bias)
    __shared__ float vs_[2][TOK];      // v (incl. qkv bias)
    __shared__ float tab2[64];         // rpb gathered, * log2e
    __shared__ float brow[31][258];    // bias rows, stride 258 (2-bank step)
    __shared__ float lpart[2][TOK];
    __shared__ float apart[2][TOK];

    const int t  = threadIdx.x;
    const int b  = blockIdx.y;
    const int d0 = blockIdx.x * 2;
    const float* q0 = qkvf + (size_t)b * (1536 * TOK);

    // phase 0: bias table (61 values)
    if (t < 61) {
        const int rel = t - 30;
        tab2[t] = rpb[rel < 0 ? rel + 961 : rel] * LOG2E;
    }
    // phase 1: stage k and v rows for the 2 channels (+qkv bias)
    {
        const int sel = t >> 7;          // 0: k, 1: v
        const int row = (t >> 6) & 1;    // dl
        const int g4  = (t & 63) * 4;
        const int o   = (sel ? 1024 : 512) + d0 + row;
        const float bb = qkv_b[o];
        float4 v = *(const float4*)(q0 + (size_t)o * TOK + g4);
        v.x += bb; v.y += bb; v.z += bb; v.w += bb;
        if (sel == 0) {
            const float s = SCALE * LOG2E;
            v.x *= s; v.y *= s; v.z *= s; v.w *= s;
            *(float4*)&ks_[row][g4] = v;
        } else {
            *(float4*)&vs_[row][g4] = v;
        }
    }
    __syncthreads();
    // phase 2: replicate bias into 31 rows x 256 g
    {
        const int rg = ((t >> 4) & 15) + (t & 15);
#pragma unroll 1
        for (int it = 0; it < 31; ++it)
            brow[it][t] = tab2[it - rg + 30];
    }
    __syncthreads();

    // phase 3: main loop
    const int w   = t >> 6;
    const int dl  = w & 1;
    const int gh  = w >> 1;
    const int hl  = t & 63;
    const int qi  = ((hl & 15) << 2) | (hl >> 4);  // bit-swizzled h-quad index
    const int h0  = qi * 4;
    const int rh0 = (qi >> 2) + 4 * (qi & 3);      // r(h0); r(h0+r)=rh0+r

    float q[4];
    {
        const float bb = qkv_b[d0 + dl];
        const float4 x4 = *(const float4*)(q0 + (size_t)(d0 + dl) * TOK + h0);
        q[0] = x4.x + bb; q[1] = x4.y + bb; q[2] = x4.z + bb; q[3] = x4.w + bb;
    }

    float l[4]  = {0.f, 0.f, 0.f, 0.f};
    float am[4] = {0.f, 0.f, 0.f, 0.f};

    const int pbeg = gh * 128;
#pragma unroll 2
    for (int p = pbeg; p < pbeg + 128; p += 4) {
        const float4 k4 = *(const float4*)&ks_[dl][p];   // wave-uniform (bcast)
        const float4 v4 = *(const float4*)&vs_[dl][p];
#pragma unroll
        for (int r = 0; r < 4; ++r) {
            const float2 b01 = *(const float2*)&brow[rh0 + r][p];
            const float2 b23 = *(const float2*)&brow[rh0 + r][p + 2];
            float e;
            e = EXP2(fmaf(q[r], k4.x, b01.x)); l[r] += e; am[r] = fmaf(e, v4.x, am[r]);
            e = EXP2(fmaf(q[r], k4.y, b01.y)); l[r] += e; am[r] = fmaf(e, v4.y, am[r]);
            e = EXP2(fmaf(q[r], k4.z, b23.x)); l[r] += e; am[r] = fmaf(e, v4.z, am[r]);
            e = EXP2(fmaf(q[r], k4.w, b23.y)); l[r] += e; am[r] = fmaf(e, v4.w, am[r]);
        }
    }

    // phase 4: merge g-halves, normalize, store as hi/lo planes (B-frag layout)
    if (gh == 1) {
        *(float4*)&lpart[dl][h0] = make_float4(l[0], l[1], l[2], l[3]);
        *(float4*)&apart[dl][h0] = make_float4(am[0], am[1], am[2], am[3]);
    }
    __syncthreads();
    if (gh == 0) {
        const float4 lo = *(const float4*)&lpart[dl][h0];
        const float4 ao = *(const float4*)&apart[dl][h0];
        float vals[4];
        vals[0] = (am[0] + ao.x) / (l[0] + lo.x);
        vals[1] = (am[1] + ao.y) / (l[1] + lo.y);
        vals[2] = (am[2] + ao.z) / (l[2] + lo.z);
        vals[3] = (am[3] + ao.w) / (l[3] + lo.w);
        const int d = d0 + dl;
        const size_t ob = (((size_t)b * 16 + (h0 >> 4)) * K8 + (d >> 3)) * 128
                          + (size_t)(h0 & 15) * 8 + (d & 7);
#pragma unroll
        for (int r = 0; r < 4; ++r) {
            const unsigned short hh = f2bf(vals[r]);
            aoh[ob + (size_t)r * 8] = hh;
            aol[ob + (size_t)r * 8] = f2bf(vals[r] - bf2f(hh));
        }
    }
}

// ---------------------------------------------------------------------------
extern "C" void kernel_launch(void* const* d_in, const int* in_sizes, int n_in,
                              void* d_out, int out_size, void* d_ws, size_t ws_size,
                              hipStream_t stream)
{
    const float* x      = (const float*)d_in[0];   // [2][512][256]
    const float* qkv_w  = (const float*)d_in[1];   // [1536][512]
    const float* qkv_b  = (const float*)d_in[2];   // [1536]
    const float* proj_w = (const float*)d_in[3];   // [512][512]
    const float* proj_b = (const float*)d_in[4];   // [512]
    const float* rpb    = (const float*)d_in[5];   // [961]
    float* out = (float*)d_out;                    // [2][512][256]

    unsigned short* U = (unsigned short*)d_ws;
    float* qkvf = (float*)d_ws + OFF_QKVF;

    // convert all GEMM operands once -> frag-tiled hi/lo planes
    prep<<<dim3(640), 256, 0, stream>>>(qkv_w, x, proj_w, U);

    // qkv = qkv_w @ x : MT=2 -> grid (48,4,2) = 384 blocks x 4 waves
    gemm_frag<2, false><<<dim3(48, 4, 2), 256, 0, stream>>>(
        U + OFF_WQAH, U + OFF_WQAL, U + OFF_XBH, U + OFF_XBL,
        nullptr, qkvf, 1536);

    // fused attention: grid (d-pairs=256, b=2); writes aout planes for proj
    attn_f32<<<dim3(256, 2), 256, 0, stream>>>(qkvf, qkv_b, rpb,
                                               U + OFF_AOBH, U + OFF_AOBL);

    // out = proj_w @ aout + proj_b : MT=1 -> grid (32,4,2) = 256 blocks
    gemm_frag<1, true><<<dim3(32, 4, 2), 256, 0, stream>>>(
        U + OFF_WPAH, U + OFF_WPAL, U + OFF_AOBH, U + OFF_AOBL,
        proj_b, out, 512);
}

// Round 7
// 97.606 us; speedup vs baseline: 5.0928x; 1.0226x over previous
//
#include <hip/hip_runtime.h>

// Problem: B=2, DIM=512, NUM_HEADS=1, tokens TOK=256 (16x16 window, w=1).
// Pipeline: [qkv GEMM: bf16 split-3 MFMA, Ksplit2] -> [fused per-channel attn, sums 2 parts]
//           -> [proj GEMM: bf16 split-3 MFMA, Ksplit4] -> [combine 4 parts + proj bias]
// fp32 in/out everywhere; GEMMs decompose operands to bf16 hi/lo during LDS
// staging and run 3 MFMAs (Ah*Bh + Al*Bh + Ah*Bl) per k-step, fp32 accum.
// This is the best-measured structure (97.1 us): conversion fused into the
// GEMM staging pipeline beats a separate prep kernel + frag-tiled planes
// (99.8 us, R4/R6) and the cooperative mega-kernel (497 us, R5).
// Workspace layout (floats):
//   qkvp  = ws + 0        : 4 parts(ks*2+b) * [1536][256] = 1,572,864
//   aout  = ws + 1572864  : [2][512][256]                 =   262,144
//   projp = ws + 1835008  : 8 parts(ks*2+b) * [512][256]  = 1,048,576
// total 2,883,584 floats = 11.5 MB of d_ws.

#define TOK    256
#define KDIM   512
#define LOG2E  1.4426950408889634f
#define SCALE  0.04419417382415922f   // 512^{-1/2}
#define QPARTS 2                      // qkv K-split parts
#define PPARTS 4                      // proj K-split parts
#define QPSTRIDE 786432               // 2*1536*256, qkv ks-part stride (fixed b)
#define PPSTRIDE 262144               // 2*512*256,  proj ks-part stride

#define EXP2(x) __builtin_amdgcn_exp2f(x)

typedef __attribute__((ext_vector_type(8))) short short8_t;  // 8 bf16 (4 VGPR)
typedef __attribute__((ext_vector_type(4))) float f32x4;     // MFMA acc

// round-to-nearest-even fp32 -> bf16 bits
__device__ __forceinline__ unsigned short f2bf(float x) {
    unsigned int u = __float_as_uint(x);
    u += 0x7fffu + ((u >> 16) & 1u);
    return (unsigned short)(u >> 16);
}
__device__ __forceinline__ float bf2f(unsigned short h) {
    return __uint_as_float((unsigned int)h << 16);
}

// ---------------------------------------------------------------------------
// bf16 split-3 MFMA GEMM, K-split.
// Cpart[z=(ks*2+b)][M][TOK] = A[M x KLEN slice] @ B[b][KLEN slice][TOK]
// Block: 256 thr = 4 waves (2m x 2n). Tile BM x 64, BK=64, full KLEN per block.
// A [M][K] fp32 -> As_h/As_l bf16 [BM][72] (16B-aligned rows, padded).
// B [K][N] fp32 -> Bs packed (hi|lo<<16) words [64n][68k] (transposed in LDS;
//   both store and frag-read are k-contiguous 16B ops -> conflict-free).
// Frags use k-chunk = (lane>>4)*8 + j for BOTH A and B (k-perm invariant).
// C/D: col = lane&15, row = (lane>>4)*4 + reg  (m89-verified mapping).
// ---------------------------------------------------------------------------
template<int BM, int KSPLIT>
__global__ __launch_bounds__(256)
void gemm_mfma(const float* __restrict__ A, const float* __restrict__ Bmat,
               float* __restrict__ C, int M)
{
    constexpr int KLEN = KDIM / KSPLIT;
    constexpr int NT   = KLEN / 64;     // K-tiles per block
    constexpr int MF   = BM / 32;       // 16-row m-frags per wave
    constexpr int AP   = BM / 16;       // float4 A loads per thread per tile
    constexpr int SA   = 72;            // As stride in ushorts (144 B rows)
    constexpr int SB   = 68;            // Bs stride in words   (272 B rows)

    __shared__ unsigned short As_h[BM * SA];
    __shared__ unsigned short As_l[BM * SA];
    __shared__ unsigned int   Bs[64 * SB];

    const int t  = threadIdx.x;
    const int o0 = blockIdx.x * BM;
    const int n0 = blockIdx.y * 64;
    const int z  = blockIdx.z;
    const int b  = z & 1;
    const int ks = z >> 1;

    const float* Ab = A + (size_t)o0 * KDIM + ks * KLEN;
    const float* Bb = Bmat + ((size_t)b * KDIM + (size_t)ks * KLEN) * TOK + n0;
    float*       Cb = C + ((size_t)z * M + o0) * TOK + n0;

    // staging maps
    const int ak4 = (t & 15) * 4;   // A k-quad
    const int am  = t >> 4;         // A row base (step 16 over p)
    const int btt = t & 63;         // B token (n)
    const int bc4 = (t >> 6) * 4;   // B k-quad base (step 16 over p)

    float4 pa[AP];
    float  pb[16];

#define LOAD_TILE(KT) do {                                                    \
        const float* ap_ = Ab + (KT) * 64 + ak4;                              \
        _Pragma("unroll")                                                     \
        for (int p = 0; p < AP; ++p)                                          \
            pa[p] = *(const float4*)(ap_ + (size_t)(am + 16 * p) * KDIM);     \
        const float* bp_ = Bb + (size_t)(KT) * 64 * TOK + btt;                \
        _Pragma("unroll")                                                     \
        for (int p = 0; p < 4; ++p)                                           \
            _Pragma("unroll")                                                 \
            for (int j = 0; j < 4; ++j)                                       \
                pb[p * 4 + j] = bp_[(size_t)(bc4 + p * 16 + j) * TOK];        \
    } while (0)

#define STORE_TILE() do {                                                     \
        _Pragma("unroll")                                                     \
        for (int p = 0; p < AP; ++p) {                                        \
            const int m_ = am + 16 * p;                                       \
            const float4 v_ = pa[p];                                          \
            const unsigned short h0 = f2bf(v_.x), h1 = f2bf(v_.y),            \
                                 h2 = f2bf(v_.z), h3 = f2bf(v_.w);            \
            const unsigned short l0 = f2bf(v_.x - bf2f(h0)),                  \
                                 l1 = f2bf(v_.y - bf2f(h1)),                  \
                                 l2 = f2bf(v_.z - bf2f(h2)),                  \
                                 l3 = f2bf(v_.w - bf2f(h3));                  \
            *(ushort4*)&As_h[(size_t)m_ * SA + ak4] =                         \
                make_ushort4(h0, h1, h2, h3);                                 \
            *(ushort4*)&As_l[(size_t)m_ * SA + ak4] =                         \
                make_ushort4(l0, l1, l2, l3);                                 \
        }                                                                     \
        _Pragma("unroll")                                                     \
        for (int p = 0; p < 4; ++p) {                                         \
            unsigned int wv0, wv1, wv2, wv3;                                  \
            {                                                                 \
                const float x0 = pb[p * 4 + 0], x1 = pb[p * 4 + 1],           \
                            x2 = pb[p * 4 + 2], x3 = pb[p * 4 + 3];           \
                const unsigned short a0 = f2bf(x0), a1 = f2bf(x1),            \
                                     a2 = f2bf(x2), a3 = f2bf(x3);            \
                wv0 = (unsigned int)a0 |                                      \
                      ((unsigned int)f2bf(x0 - bf2f(a0)) << 16);              \
                wv1 = (unsigned int)a1 |                                      \
                      ((unsigned int)f2bf(x1 - bf2f(a1)) << 16);              \
                wv2 = (unsigned int)a2 |                                      \
                      ((unsigned int)f2bf(x2 - bf2f(a2)) << 16);              \
                wv3 = (unsigned int)a3 |                                      \
                      ((unsigned int)f2bf(x3 - bf2f(a3)) << 16);              \
            }                                                                 \
            *(uint4*)&Bs[(size_t)btt * SB + bc4 + p * 16] =                   \
                make_uint4(wv0, wv1, wv2, wv3);                               \
        }                                                                     \
    } while (0)

    // wave decomposition: 2 m-waves x 2 n-waves; wave tile (BM/2) x 32
    const int wid  = t >> 6;
    const int wm   = wid & 1;
    const int wn   = wid >> 1;
    const int lane = t & 63;
    const int lr   = lane & 15;   // frag row (A) / col (B,D)
    const int lg   = lane >> 4;   // k-chunk group / D row-quad

    const int mwb = wm * (BM / 2);
    const int nwb = wn * 32;

    f32x4 acc[MF][2];
#pragma unroll
    for (int mi = 0; mi < MF; ++mi)
#pragma unroll
        for (int ni = 0; ni < 2; ++ni)
            acc[mi][ni] = (f32x4){0.f, 0.f, 0.f, 0.f};

    LOAD_TILE(0);
    STORE_TILE();
    __syncthreads();

#pragma unroll
    for (int kt = 0; kt < NT; ++kt) {
        if (kt + 1 < NT) LOAD_TILE(kt + 1);   // prefetch next tile to regs

#pragma unroll
        for (int ksp = 0; ksp < 2; ++ksp) {   // two K=32 steps per tile
            const int kb = ksp * 32 + lg * 8; // elem (ushort/word) offset

            short8_t ah[MF], al[MF];
#pragma unroll
            for (int mi = 0; mi < MF; ++mi) {
                const int m_ = mwb + mi * 16 + lr;
                ah[mi] = *(const short8_t*)&As_h[(size_t)m_ * SA + kb];
                al[mi] = *(const short8_t*)&As_l[(size_t)m_ * SA + kb];
            }

            short8_t bh[2], bl[2];
#pragma unroll
            for (int ni = 0; ni < 2; ++ni) {
                const unsigned int* wp =
                    &Bs[(size_t)(nwb + ni * 16 + lr) * SB + kb];
                const uint4 w0 = *(const uint4*)wp;
                const uint4 w1 = *(const uint4*)(wp + 4);
                short8_t h_, l_;
                h_[0] = (short)(w0.x & 0xffffu); l_[0] = (short)(w0.x >> 16);
                h_[1] = (short)(w0.y & 0xffffu); l_[1] = (short)(w0.y >> 16);
                h_[2] = (short)(w0.z & 0xffffu); l_[2] = (short)(w0.z >> 16);
                h_[3] = (short)(w0.w & 0xffffu); l_[3] = (short)(w0.w >> 16);
                h_[4] = (short)(w1.x & 0xffffu); l_[4] = (short)(w1.x >> 16);
                h_[5] = (short)(w1.y & 0xffffu); l_[5] = (short)(w1.y >> 16);
                h_[6] = (short)(w1.z & 0xffffu); l_[6] = (short)(w1.z >> 16);
                h_[7] = (short)(w1.w & 0xffffu); l_[7] = (short)(w1.w >> 16);
                bh[ni] = h_; bl[ni] = l_;
            }

#pragma unroll
            for (int mi = 0; mi < MF; ++mi)
#pragma unroll
                for (int ni = 0; ni < 2; ++ni) {
                    acc[mi][ni] = __builtin_amdgcn_mfma_f32_16x16x32_bf16(
                        ah[mi], bh[ni], acc[mi][ni], 0, 0, 0);
                    acc[mi][ni] = __builtin_amdgcn_mfma_f32_16x16x32_bf16(
                        al[mi], bh[ni], acc[mi][ni], 0, 0, 0);
                    acc[mi][ni] = __builtin_amdgcn_mfma_f32_16x16x32_bf16(
                        ah[mi], bl[ni], acc[mi][ni], 0, 0, 0);
                }
        }

        if (kt + 1 < NT) {
            __syncthreads();
            STORE_TILE();
            __syncthreads();
        }
    }

    // epilogue: D frag -> global (lanes 0..15 of each quad write one row)
#pragma unroll
    for (int mi = 0; mi < MF; ++mi)
#pragma unroll
        for (int ni = 0; ni < 2; ++ni)
#pragma unroll
            for (int r = 0; r < 4; ++r) {
                const int row = mwb + mi * 16 + lg * 4 + r;
                const int col = nwb + ni * 16 + lr;
                Cb[(size_t)row * TOK + col] = acc[mi][ni][r];
            }
#undef LOAD_TILE
#undef STORE_TILE
}

// ---------------------------------------------------------------------------
// Fused per-channel attention (sums the 2 qkv K-split parts inline).
// Block = 256 threads handles (b, d0..d0+1): waves = (dl, g-half).
// bias[h,g] = tab[r(h)-r(g)+30], r(h)=(h>>4)+(h&15): 61 distinct values,
// replicated into brow[31][258] (2-bank step, conflict-free float2 reads).
// Scores bounded (~1.1) -> no max-subtraction; g-half partials merge additively.
// ---------------------------------------------------------------------------
__global__ __launch_bounds__(256)
void attn_f32(const float* __restrict__ qkvp, const float* __restrict__ qkv_b,
              const float* __restrict__ rpb, float* __restrict__ aout)
{
    __shared__ float ks_[2][TOK];      // k * scale * log2e (incl. qkv bias)
    __shared__ float vs_[2][TOK];      // v (incl. qkv bias)
    __shared__ float tab2[64];         // rpb gathered, * log2e
    __shared__ float brow[31][258];    // bias rows, stride 258 (2-bank step)
    __shared__ float lpart[2][TOK];
    __shared__ float apart[2][TOK];

    const int t  = threadIdx.x;
    const int b  = blockIdx.y;
    const int d0 = blockIdx.x * 2;
    const float* q0 = qkvp + (size_t)b * (1536 * TOK);

    // phase 0: bias table (61 values)
    if (t < 61) {
        const int rel = t - 30;
        tab2[t] = rpb[rel < 0 ? rel + 961 : rel] * LOG2E;
    }
    // phase 1: stage k and v for the 2 channels (sum 2 K-split parts + bias)
    {
        const int sel = t >> 7;          // 0: k, 1: v
        const int row = (t >> 6) & 1;    // dl
        const int g4  = (t & 63) * 4;
        const int o   = (sel ? 1024 : 512) + d0 + row;
        const float* p = q0 + (size_t)o * TOK + g4;
        const float bb = qkv_b[o];
        float4 v = make_float4(bb, bb, bb, bb);
#pragma unroll
        for (int pp = 0; pp < QPARTS; ++pp) {
            const float4 x = *(const float4*)(p + (size_t)pp * QPSTRIDE);
            v.x += x.x; v.y += x.y; v.z += x.z; v.w += x.w;
        }
        if (sel == 0) {
            const float s = SCALE * LOG2E;
            v.x *= s; v.y *= s; v.z *= s; v.w *= s;
            *(float4*)&ks_[row][g4] = v;
        } else {
            *(float4*)&vs_[row][g4] = v;
        }
    }
    __syncthreads();
    // phase 2: replicate bias into 31 rows x 256 g
    {
        const int rg = ((t >> 4) & 15) + (t & 15);
#pragma unroll 1
        for (int it = 0; it < 31; ++it)
            brow[it][t] = tab2[it - rg + 30];
    }
    __syncthreads();

    // phase 3: main loop
    const int w   = t >> 6;
    const int dl  = w & 1;
    const int gh  = w >> 1;
    const int hl  = t & 63;
    const int qi  = ((hl & 15) << 2) | (hl >> 4);  // bit-swizzled h-quad index
    const int h0  = qi * 4;
    const int rh0 = (qi >> 2) + 4 * (qi & 3);      // r(h0); r(h0+r)=rh0+r

    float q[4];
    {
        const float* p = q0 + (size_t)(d0 + dl) * TOK + h0;
        const float bb = qkv_b[d0 + dl];
        q[0] = bb; q[1] = bb; q[2] = bb; q[3] = bb;
#pragma unroll
        for (int pp = 0; pp < QPARTS; ++pp) {
            const float4 x = *(const float4*)(p + (size_t)pp * QPSTRIDE);
            q[0] += x.x; q[1] += x.y; q[2] += x.z; q[3] += x.w;
        }
    }

    float l[4]  = {0.f, 0.f, 0.f, 0.f};
    float am[4] = {0.f, 0.f, 0.f, 0.f};

    const int pbeg = gh * 128;
#pragma unroll 2
    for (int p = pbeg; p < pbeg + 128; p += 4) {
        const float4 k4 = *(const float4*)&ks_[dl][p];   // wave-uniform (bcast)
        const float4 v4 = *(const float4*)&vs_[dl][p];
#pragma unroll
        for (int r = 0; r < 4; ++r) {
            const float2 b01 = *(const float2*)&brow[rh0 + r][p];
            const float2 b23 = *(const float2*)&brow[rh0 + r][p + 2];
            float e;
            e = EXP2(fmaf(q[r], k4.x, b01.x)); l[r] += e; am[r] = fmaf(e, v4.x, am[r]);
            e = EXP2(fmaf(q[r], k4.y, b01.y)); l[r] += e; am[r] = fmaf(e, v4.y, am[r]);
            e = EXP2(fmaf(q[r], k4.z, b23.x)); l[r] += e; am[r] = fmaf(e, v4.z, am[r]);
            e = EXP2(fmaf(q[r], k4.w, b23.y)); l[r] += e; am[r] = fmaf(e, v4.w, am[r]);
        }
    }

    // phase 4: merge g-halves, normalize, store
    if (gh == 1) {
        *(float4*)&lpart[dl][h0] = make_float4(l[0], l[1], l[2], l[3]);
        *(float4*)&apart[dl][h0] = make_float4(am[0], am[1], am[2], am[3]);
    }
    __syncthreads();
    if (gh == 0) {
        const float4 lo = *(const float4*)&lpart[dl][h0];
        const float4 ao = *(const float4*)&apart[dl][h0];
        float4 o4;
        o4.x = (am[0] + ao.x) / (l[0] + lo.x);
        o4.y = (am[1] + ao.y) / (l[1] + lo.y);
        o4.z = (am[2] + ao.z) / (l[2] + lo.z);
        o4.w = (am[3] + ao.w) / (l[3] + lo.w);
        *(float4*)(aout + ((size_t)b * 512 + d0 + dl) * TOK + h0) = o4;
    }
}

// ---------------------------------------------------------------------------
// Sum the 4 proj K-split parts + proj bias -> final output [2][512][256]
// ---------------------------------------------------------------------------
__global__ __launch_bounds__(256)
void combine_f32(const float* __restrict__ pp, const float* __restrict__ pb,
                 float* __restrict__ out)
{
    const int gid  = blockIdx.x * 256 + threadIdx.x;
    const int flat = gid * 4;
    const int o = (flat >> 8) & 511;
    float4 a = make_float4(pb[o], pb[o], pb[o], pb[o]);
#pragma unroll
    for (int p = 0; p < PPARTS; ++p) {
        const float4 x = *(const float4*)(pp + (size_t)p * PPSTRIDE + flat);
        a.x += x.x; a.y += x.y; a.z += x.z; a.w += x.w;
    }
    *(float4*)(out + flat) = a;
}

// ---------------------------------------------------------------------------
extern "C" void kernel_launch(void* const* d_in, const int* in_sizes, int n_in,
                              void* d_out, int out_size, void* d_ws, size_t ws_size,
                              hipStream_t stream)
{
    const float* x      = (const float*)d_in[0];   // [2][512][256]
    const float* qkv_w  = (const float*)d_in[1];   // [1536][512]
    const float* qkv_b  = (const float*)d_in[2];   // [1536]
    const float* proj_w = (const float*)d_in[3];   // [512][512]
    const float* proj_b = (const float*)d_in[4];   // [512]
    const float* rpb    = (const float*)d_in[5];   // [961]
    float* out = (float*)d_out;                    // [2][512][256]
    float* ws  = (float*)d_ws;

    float* qkvp  = ws;                 // 4 * 393216
    float* aout  = ws + 1572864;       // 262144
    float* projp = ws + 1835008;       // 8 * 131072

    // qkv = qkv_w @ x: M=1536, BM=128, Ksplit=2 -> grid (12, 4, 4) = 192 blocks
    gemm_mfma<128, 2><<<dim3(12, 4, 4), 256, 0, stream>>>(qkv_w, x, qkvp, 1536);

    // fused attention: grid (d-pairs=256, b=2), sums 2 qkv parts inline
    attn_f32<<<dim3(256, 2), 256, 0, stream>>>(qkvp, qkv_b, rpb, aout);

    // proj = proj_w @ aout: M=512, BM=64, Ksplit=4 -> grid (8, 4, 8) = 256 blocks
    gemm_mfma<64, 4><<<dim3(8, 4, 8), 256, 0, stream>>>(proj_w, aout, projp, 512);

    // sum 4 parts + bias
    combine_f32<<<dim3(256), 256, 0, stream>>>(projp, proj_b, out);
}

// Round 8
// 96.892 us; speedup vs baseline: 5.1303x; 1.0074x over previous
//
#include <hip/hip_runtime.h>

// Problem: B=2, DIM=512, NUM_HEADS=1, tokens TOK=256 (16x16 window, w=1).
// Pipeline: [qkv GEMM: bf16 split-3 MFMA, Ksplit8, NT=1] -> [attn, sums 8 parts]
//           -> [proj GEMM: Ksplit8, NT=1] -> [combine 8 parts + proj bias]
// fp32 in/out everywhere; GEMMs decompose operands to bf16 hi/lo during LDS
// staging and run 3 MFMAs (Ah*Bh + Al*Bh + Ah*Bl) per k-step, fp32 accum.
// R7 lesson (rocprof): KSPLIT=2 qkv gemm = 192 blocks, NT=4 serial tile chain,
// Occupancy 7.4%, MfmaUtil 1.9% -> latency-bound, worst after the harness's
// 256MiB L2-evicting workspace fills. KSPLIT=8/BM=64 -> 1536/512 blocks, NT=1:
// single-shot load->convert->MFMA per block, max parallel cold misses.
// Workspace layout (floats) — R0-verified offsets:
//   qkvp  = ws + 0        : 16 parts(ks*2+b) * [1536][256] = 6,291,456
//   aout  = ws + 6291456  : [2][512][256]                  =   262,144
//   projp = ws + 6553600  : 16 parts(ks*2+b) * [512][256]  = 2,097,152

#define TOK    256
#define KDIM   512
#define LOG2E  1.4426950408889634f
#define SCALE  0.04419417382415922f   // 512^{-1/2}
#define QPARTS 8                      // qkv K-split parts
#define PPARTS 8                      // proj K-split parts
#define QPSTRIDE 786432               // 2*1536*256, qkv ks-part stride (fixed b)
#define PPSTRIDE 262144               // 2*512*256,  proj ks-part stride

#define EXP2(x) __builtin_amdgcn_exp2f(x)

typedef __attribute__((ext_vector_type(8))) short short8_t;  // 8 bf16 (4 VGPR)
typedef __attribute__((ext_vector_type(4))) float f32x4;     // MFMA acc

// round-to-nearest-even fp32 -> bf16 bits
__device__ __forceinline__ unsigned short f2bf(float x) {
    unsigned int u = __float_as_uint(x);
    u += 0x7fffu + ((u >> 16) & 1u);
    return (unsigned short)(u >> 16);
}
__device__ __forceinline__ float bf2f(unsigned short h) {
    return __uint_as_float((unsigned int)h << 16);
}

// ---------------------------------------------------------------------------
// bf16 split-3 MFMA GEMM, K-split.
// Cpart[z=(ks*2+b)][M][TOK] = A[M x KLEN slice] @ B[b][KLEN slice][TOK]
// Block: 256 thr = 4 waves (2m x 2n). Tile BM x 64, BK=64, full KLEN per block.
// A [M][K] fp32 -> As_h/As_l bf16 [BM][72] (16B-aligned rows, padded).
// B [K][N] fp32 -> Bs packed (hi|lo<<16) words [64n][68k] (transposed in LDS;
//   both store and frag-read are k-contiguous 16B ops -> conflict-free).
// Frags use k-chunk = (lane>>4)*8 + j for BOTH A and B (k-perm invariant).
// C/D: col = lane&15, row = (lane>>4)*4 + reg  (m89-verified mapping).
// KSPLIT=8 -> KLEN=64, NT=1: no tile loop, no prefetch, single barrier.
// ---------------------------------------------------------------------------
template<int BM, int KSPLIT>
__global__ __launch_bounds__(256)
void gemm_mfma(const float* __restrict__ A, const float* __restrict__ Bmat,
               float* __restrict__ C, int M)
{
    constexpr int KLEN = KDIM / KSPLIT;
    constexpr int NT   = KLEN / 64;     // K-tiles per block
    constexpr int MF   = BM / 32;       // 16-row m-frags per wave
    constexpr int AP   = BM / 16;       // float4 A loads per thread per tile
    constexpr int SA   = 72;            // As stride in ushorts (144 B rows)
    constexpr int SB   = 68;            // Bs stride in words   (272 B rows)

    __shared__ unsigned short As_h[BM * SA];
    __shared__ unsigned short As_l[BM * SA];
    __shared__ unsigned int   Bs[64 * SB];

    const int t  = threadIdx.x;
    const int o0 = blockIdx.x * BM;
    const int n0 = blockIdx.y * 64;
    const int z  = blockIdx.z;
    const int b  = z & 1;
    const int ks = z >> 1;

    const float* Ab = A + (size_t)o0 * KDIM + ks * KLEN;
    const float* Bb = Bmat + ((size_t)b * KDIM + (size_t)ks * KLEN) * TOK + n0;
    float*       Cb = C + ((size_t)z * M + o0) * TOK + n0;

    // staging maps
    const int ak4 = (t & 15) * 4;   // A k-quad
    const int am  = t >> 4;         // A row base (step 16 over p)
    const int btt = t & 63;         // B token (n)
    const int bc4 = (t >> 6) * 4;   // B k-quad base (step 16 over p)

    float4 pa[AP];
    float  pb[16];

#define LOAD_TILE(KT) do {                                                    \
        const float* ap_ = Ab + (KT) * 64 + ak4;                              \
        _Pragma("unroll")                                                     \
        for (int p = 0; p < AP; ++p)                                          \
            pa[p] = *(const float4*)(ap_ + (size_t)(am + 16 * p) * KDIM);     \
        const float* bp_ = Bb + (size_t)(KT) * 64 * TOK + btt;                \
        _Pragma("unroll")                                                     \
        for (int p = 0; p < 4; ++p)                                           \
            _Pragma("unroll")                                                 \
            for (int j = 0; j < 4; ++j)                                       \
                pb[p * 4 + j] = bp_[(size_t)(bc4 + p * 16 + j) * TOK];        \
    } while (0)

#define STORE_TILE() do {                                                     \
        _Pragma("unroll")                                                     \
        for (int p = 0; p < AP; ++p) {                                        \
            const int m_ = am + 16 * p;                                       \
            const float4 v_ = pa[p];                                          \
            const unsigned short h0 = f2bf(v_.x), h1 = f2bf(v_.y),            \
                                 h2 = f2bf(v_.z), h3 = f2bf(v_.w);            \
            const unsigned short l0 = f2bf(v_.x - bf2f(h0)),                  \
                                 l1 = f2bf(v_.y - bf2f(h1)),                  \
                                 l2 = f2bf(v_.z - bf2f(h2)),                  \
                                 l3 = f2bf(v_.w - bf2f(h3));                  \
            *(ushort4*)&As_h[(size_t)m_ * SA + ak4] =                         \
                make_ushort4(h0, h1, h2, h3);                                 \
            *(ushort4*)&As_l[(size_t)m_ * SA + ak4] =                         \
                make_ushort4(l0, l1, l2, l3);                                 \
        }                                                                     \
        _Pragma("unroll")                                                     \
        for (int p = 0; p < 4; ++p) {                                         \
            unsigned int wv0, wv1, wv2, wv3;                                  \
            {                                                                 \
                const float x0 = pb[p * 4 + 0], x1 = pb[p * 4 + 1],           \
                            x2 = pb[p * 4 + 2], x3 = pb[p * 4 + 3];           \
                const unsigned short a0 = f2bf(x0), a1 = f2bf(x1),            \
                                     a2 = f2bf(x2), a3 = f2bf(x3);            \
                wv0 = (unsigned int)a0 |                                      \
                      ((unsigned int)f2bf(x0 - bf2f(a0)) << 16);              \
                wv1 = (unsigned int)a1 |                                      \
                      ((unsigned int)f2bf(x1 - bf2f(a1)) << 16);              \
                wv2 = (unsigned int)a2 |                                      \
                      ((unsigned int)f2bf(x2 - bf2f(a2)) << 16);              \
                wv3 = (unsigned int)a3 |                                      \
                      ((unsigned int)f2bf(x3 - bf2f(a3)) << 16);              \
            }                                                                 \
            *(uint4*)&Bs[(size_t)btt * SB + bc4 + p * 16] =                   \
                make_uint4(wv0, wv1, wv2, wv3);                               \
        }                                                                     \
    } while (0)

    // wave decomposition: 2 m-waves x 2 n-waves; wave tile (BM/2) x 32
    const int wid  = t >> 6;
    const int wm   = wid & 1;
    const int wn   = wid >> 1;
    const int lane = t & 63;
    const int lr   = lane & 15;   // frag row (A) / col (B,D)
    const int lg   = lane >> 4;   // k-chunk group / D row-quad

    const int mwb = wm * (BM / 2);
    const int nwb = wn * 32;

    f32x4 acc[MF][2];
#pragma unroll
    for (int mi = 0; mi < MF; ++mi)
#pragma unroll
        for (int ni = 0; ni < 2; ++ni)
            acc[mi][ni] = (f32x4){0.f, 0.f, 0.f, 0.f};

    LOAD_TILE(0);
    STORE_TILE();
    __syncthreads();

#pragma unroll
    for (int kt = 0; kt < NT; ++kt) {
        if (kt + 1 < NT) LOAD_TILE(kt + 1);   // prefetch next tile to regs

#pragma unroll
        for (int ksp = 0; ksp < 2; ++ksp) {   // two K=32 steps per tile
            const int kb = ksp * 32 + lg * 8; // elem (ushort/word) offset

            short8_t ah[MF], al[MF];
#pragma unroll
            for (int mi = 0; mi < MF; ++mi) {
                const int m_ = mwb + mi * 16 + lr;
                ah[mi] = *(const short8_t*)&As_h[(size_t)m_ * SA + kb];
                al[mi] = *(const short8_t*)&As_l[(size_t)m_ * SA + kb];
            }

            short8_t bh[2], bl[2];
#pragma unroll
            for (int ni = 0; ni < 2; ++ni) {
                const unsigned int* wp =
                    &Bs[(size_t)(nwb + ni * 16 + lr) * SB + kb];
                const uint4 w0 = *(const uint4*)wp;
                const uint4 w1 = *(const uint4*)(wp + 4);
                short8_t h_, l_;
                h_[0] = (short)(w0.x & 0xffffu); l_[0] = (short)(w0.x >> 16);
                h_[1] = (short)(w0.y & 0xffffu); l_[1] = (short)(w0.y >> 16);
                h_[2] = (short)(w0.z & 0xffffu); l_[2] = (short)(w0.z >> 16);
                h_[3] = (short)(w0.w & 0xffffu); l_[3] = (short)(w0.w >> 16);
                h_[4] = (short)(w1.x & 0xffffu); l_[4] = (short)(w1.x >> 16);
                h_[5] = (short)(w1.y & 0xffffu); l_[5] = (short)(w1.y >> 16);
                h_[6] = (short)(w1.z & 0xffffu); l_[6] = (short)(w1.z >> 16);
                h_[7] = (short)(w1.w & 0xffffu); l_[7] = (short)(w1.w >> 16);
                bh[ni] = h_; bl[ni] = l_;
            }

#pragma unroll
            for (int mi = 0; mi < MF; ++mi)
#pragma unroll
                for (int ni = 0; ni < 2; ++ni) {
                    acc[mi][ni] = __builtin_amdgcn_mfma_f32_16x16x32_bf16(
                        ah[mi], bh[ni], acc[mi][ni], 0, 0, 0);
                    acc[mi][ni] = __builtin_amdgcn_mfma_f32_16x16x32_bf16(
                        al[mi], bh[ni], acc[mi][ni], 0, 0, 0);
                    acc[mi][ni] = __builtin_amdgcn_mfma_f32_16x16x32_bf16(
                        ah[mi], bl[ni], acc[mi][ni], 0, 0, 0);
                }
        }

        if (kt + 1 < NT) {
            __syncthreads();
            STORE_TILE();
            __syncthreads();
        }
    }

    // epilogue: D frag -> global (lanes 0..15 of each quad write one row)
#pragma unroll
    for (int mi = 0; mi < MF; ++mi)
#pragma unroll
        for (int ni = 0; ni < 2; ++ni)
#pragma unroll
            for (int r = 0; r < 4; ++r) {
                const int row = mwb + mi * 16 + lg * 4 + r;
                const int col = nwb + ni * 16 + lr;
                Cb[(size_t)row * TOK + col] = acc[mi][ni][r];
            }
#undef LOAD_TILE
#undef STORE_TILE
}

// ---------------------------------------------------------------------------
// Fused per-channel attention (sums the 8 qkv K-split parts inline).
// Block = 256 threads handles (b, d0..d0+1): waves = (dl, g-half).
// bias[h,g] = tab[r(h)-r(g)+30], r(h)=(h>>4)+(h&15): 61 distinct values,
// replicated into brow[31][258] (2-bank step, conflict-free float2 reads).
// Scores bounded (~1.1) -> no max-subtraction; g-half partials merge additively.
// ---------------------------------------------------------------------------
__global__ __launch_bounds__(256)
void attn_f32(const float* __restrict__ qkvp, const float* __restrict__ qkv_b,
              const float* __restrict__ rpb, float* __restrict__ aout)
{
    __shared__ float ks_[2][TOK];      // k * scale * log2e (incl. qkv bias)
    __shared__ float vs_[2][TOK];      // v (incl. qkv bias)
    __shared__ float tab2[64];         // rpb gathered, * log2e
    __shared__ float brow[31][258];    // bias rows, stride 258 (2-bank step)
    __shared__ float lpart[2][TOK];
    __shared__ float apart[2][TOK];

    const int t  = threadIdx.x;
    const int b  = blockIdx.y;
    const int d0 = blockIdx.x * 2;
    const float* q0 = qkvp + (size_t)b * (1536 * TOK);

    // phase 0: bias table (61 values)
    if (t < 61) {
        const int rel = t - 30;
        tab2[t] = rpb[rel < 0 ? rel + 961 : rel] * LOG2E;
    }
    // phase 1: stage k and v for the 2 channels (sum 8 K-split parts + bias)
    {
        const int sel = t >> 7;          // 0: k, 1: v
        const int row = (t >> 6) & 1;    // dl
        const int g4  = (t & 63) * 4;
        const int o   = (sel ? 1024 : 512) + d0 + row;
        const float* p = q0 + (size_t)o * TOK + g4;
        const float bb = qkv_b[o];
        float4 v = make_float4(bb, bb, bb, bb);
#pragma unroll
        for (int pp = 0; pp < QPARTS; ++pp) {
            const float4 x = *(const float4*)(p + (size_t)pp * QPSTRIDE);
            v.x += x.x; v.y += x.y; v.z += x.z; v.w += x.w;
        }
        if (sel == 0) {
            const float s = SCALE * LOG2E;
            v.x *= s; v.y *= s; v.z *= s; v.w *= s;
            *(float4*)&ks_[row][g4] = v;
        } else {
            *(float4*)&vs_[row][g4] = v;
        }
    }
    __syncthreads();
    // phase 2: replicate bias into 31 rows x 256 g
    {
        const int rg = ((t >> 4) & 15) + (t & 15);
#pragma unroll 1
        for (int it = 0; it < 31; ++it)
            brow[it][t] = tab2[it - rg + 30];
    }
    __syncthreads();

    // phase 3: main loop
    const int w   = t >> 6;
    const int dl  = w & 1;
    const int gh  = w >> 1;
    const int hl  = t & 63;
    const int qi  = ((hl & 15) << 2) | (hl >> 4);  // bit-swizzled h-quad index
    const int h0  = qi * 4;
    const int rh0 = (qi >> 2) + 4 * (qi & 3);      // r(h0); r(h0+r)=rh0+r

    float q[4];
    {
        const float* p = q0 + (size_t)(d0 + dl) * TOK + h0;
        const float bb = qkv_b[d0 + dl];
        q[0] = bb; q[1] = bb; q[2] = bb; q[3] = bb;
#pragma unroll
        for (int pp = 0; pp < QPARTS; ++pp) {
            const float4 x = *(const float4*)(p + (size_t)pp * QPSTRIDE);
            q[0] += x.x; q[1] += x.y; q[2] += x.z; q[3] += x.w;
        }
    }

    float l[4]  = {0.f, 0.f, 0.f, 0.f};
    float am[4] = {0.f, 0.f, 0.f, 0.f};

    const int pbeg = gh * 128;
#pragma unroll 2
    for (int p = pbeg; p < pbeg + 128; p += 4) {
        const float4 k4 = *(const float4*)&ks_[dl][p];   // wave-uniform (bcast)
        const float4 v4 = *(const float4*)&vs_[dl][p];
#pragma unroll
        for (int r = 0; r < 4; ++r) {
            const float2 b01 = *(const float2*)&brow[rh0 + r][p];
            const float2 b23 = *(const float2*)&brow[rh0 + r][p + 2];
            float e;
            e = EXP2(fmaf(q[r], k4.x, b01.x)); l[r] += e; am[r] = fmaf(e, v4.x, am[r]);
            e = EXP2(fmaf(q[r], k4.y, b01.y)); l[r] += e; am[r] = fmaf(e, v4.y, am[r]);
            e = EXP2(fmaf(q[r], k4.z, b23.x)); l[r] += e; am[r] = fmaf(e, v4.z, am[r]);
            e = EXP2(fmaf(q[r], k4.w, b23.y)); l[r] += e; am[r] = fmaf(e, v4.w, am[r]);
        }
    }

    // phase 4: merge g-halves, normalize, store
    if (gh == 1) {
        *(float4*)&lpart[dl][h0] = make_float4(l[0], l[1], l[2], l[3]);
        *(float4*)&apart[dl][h0] = make_float4(am[0], am[1], am[2], am[3]);
    }
    __syncthreads();
    if (gh == 0) {
        const float4 lo = *(const float4*)&lpart[dl][h0];
        const float4 ao = *(const float4*)&apart[dl][h0];
        float4 o4;
        o4.x = (am[0] + ao.x) / (l[0] + lo.x);
        o4.y = (am[1] + ao.y) / (l[1] + lo.y);
        o4.z = (am[2] + ao.z) / (l[2] + lo.z);
        o4.w = (am[3] + ao.w) / (l[3] + lo.w);
        *(float4*)(aout + ((size_t)b * 512 + d0 + dl) * TOK + h0) = o4;
    }
}

// ---------------------------------------------------------------------------
// Sum the 8 proj K-split parts + proj bias -> final output [2][512][256]
// ---------------------------------------------------------------------------
__global__ __launch_bounds__(256)
void combine_f32(const float* __restrict__ pp, const float* __restrict__ pb,
                 float* __restrict__ out)
{
    const int gid  = blockIdx.x * 256 + threadIdx.x;
    const int flat = gid * 4;
    const int o = (flat >> 8) & 511;
    float4 a = make_float4(pb[o], pb[o], pb[o], pb[o]);
#pragma unroll
    for (int p = 0; p < PPARTS; ++p) {
        const float4 x = *(const float4*)(pp + (size_t)p * PPSTRIDE + flat);
        a.x += x.x; a.y += x.y; a.z += x.z; a.w += x.w;
    }
    *(float4*)(out + flat) = a;
}

// ---------------------------------------------------------------------------
extern "C" void kernel_launch(void* const* d_in, const int* in_sizes, int n_in,
                              void* d_out, int out_size, void* d_ws, size_t ws_size,
                              hipStream_t stream)
{
    const float* x      = (const float*)d_in[0];   // [2][512][256]
    const float* qkv_w  = (const float*)d_in[1];   // [1536][512]
    const float* qkv_b  = (const float*)d_in[2];   // [1536]
    const float* proj_w = (const float*)d_in[3];   // [512][512]
    const float* proj_b = (const float*)d_in[4];   // [512]
    const float* rpb    = (const float*)d_in[5];   // [961]
    float* out = (float*)d_out;                    // [2][512][256]
    float* ws  = (float*)d_ws;

    float* qkvp  = ws;                 // 16 * 393216
    float* aout  = ws + 6291456;       // 262144
    float* projp = ws + 6553600;       // 16 * 131072

    // qkv = qkv_w @ x: M=1536, BM=64, Ksplit=8 -> grid (24,4,16) = 1536 blocks
    gemm_mfma<64, 8><<<dim3(24, 4, 16), 256, 0, stream>>>(qkv_w, x, qkvp, 1536);

    // fused attention: grid (d-pairs=256, b=2), sums 8 qkv parts inline
    attn_f32<<<dim3(256, 2), 256, 0, stream>>>(qkvp, qkv_b, rpb, aout);

    // proj = proj_w @ aout: M=512, BM=64, Ksplit=8 -> grid (8,4,16) = 512 blocks
    gemm_mfma<64, 8><<<dim3(8, 4, 16), 256, 0, stream>>>(proj_w, aout, projp, 512);

    // sum 8 parts + bias
    combine_f32<<<dim3(256), 256, 0, stream>>>(projp, proj_b, out);
}

// Round 9
// 96.434 us; speedup vs baseline: 5.1547x; 1.0048x over previous
//
#include <hip/hip_runtime.h>

// Problem: B=2, DIM=512, NUM_HEADS=1, tokens TOK=256 (16x16 window, w=1).
// Pipeline: [qkv GEMM: bf16 split-3 MFMA, Ksplit4, NT=2] -> [attn, sums 4 parts]
//           -> [proj GEMM: Ksplit4, NT=2] -> [combine 4 parts + proj bias]
// fp32 in/out everywhere; GEMMs decompose operands to bf16 hi/lo during LDS
// staging and run 3 MFMAs (Ah*Bh + Al*Bh + Ah*Bl) per k-step, fp32 accum.
// Evolution: R7 (Ksplit2, 192 blocks, NT=4) = latency-bound ramp (Occ 7.4%,
// MfmaUtil 1.9%). R8 (Ksplit8, 1536 blocks, NT=1) = 96.9 best, but 25MB of
// part round-trip. This round: Ksplit4 = 768/256 blocks, NT=2 — keeps the
// parallel ramp, halves part traffic (qkvp 25.2->12.6MB, projp 8.4->4.2MB).
// Workspace layout (floats):
//   qkvp  = ws + 0        : 8 parts(ks*2+b) * [1536][256] = 3,145,728
//   aout  = ws + 3145728  : [2][512][256]                 =   262,144
//   projp = ws + 3407872  : 8 parts(ks*2+b) * [512][256]  = 1,048,576
// total 4,456,448 floats = 17.8 MB of d_ws.

#define TOK    256
#define KDIM   512
#define LOG2E  1.4426950408889634f
#define SCALE  0.04419417382415922f   // 512^{-1/2}
#define QPARTS 4                      // qkv K-split parts
#define PPARTS 4                      // proj K-split parts
#define QPSTRIDE 786432               // 2*1536*256, qkv ks-part stride (fixed b)
#define PPSTRIDE 262144               // 2*512*256,  proj ks-part stride

#define EXP2(x) __builtin_amdgcn_exp2f(x)

typedef __attribute__((ext_vector_type(8))) short short8_t;  // 8 bf16 (4 VGPR)
typedef __attribute__((ext_vector_type(4))) float f32x4;     // MFMA acc

// round-to-nearest-even fp32 -> bf16 bits
__device__ __forceinline__ unsigned short f2bf(float x) {
    unsigned int u = __float_as_uint(x);
    u += 0x7fffu + ((u >> 16) & 1u);
    return (unsigned short)(u >> 16);
}
__device__ __forceinline__ float bf2f(unsigned short h) {
    return __uint_as_float((unsigned int)h << 16);
}

// ---------------------------------------------------------------------------
// bf16 split-3 MFMA GEMM, K-split.
// Cpart[z=(ks*2+b)][M][TOK] = A[M x KLEN slice] @ B[b][KLEN slice][TOK]
// Block: 256 thr = 4 waves (2m x 2n). Tile BM x 64, BK=64, KLEN=128 -> NT=2.
// A [M][K] fp32 -> As_h/As_l bf16 [BM][72] (16B-aligned rows, padded).
// B [K][N] fp32 -> Bs packed (hi|lo<<16) words [64n][68k] (transposed in LDS;
//   both store and frag-read are k-contiguous 16B ops -> conflict-free).
// Frags use k-chunk = (lane>>4)*8 + j for BOTH A and B (k-perm invariant).
// C/D: col = lane&15, row = (lane>>4)*4 + reg  (m89-verified mapping).
// ---------------------------------------------------------------------------
template<int BM, int KSPLIT>
__global__ __launch_bounds__(256)
void gemm_mfma(const float* __restrict__ A, const float* __restrict__ Bmat,
               float* __restrict__ C, int M)
{
    constexpr int KLEN = KDIM / KSPLIT;
    constexpr int NT   = KLEN / 64;     // K-tiles per block
    constexpr int MF   = BM / 32;       // 16-row m-frags per wave
    constexpr int AP   = BM / 16;       // float4 A loads per thread per tile
    constexpr int SA   = 72;            // As stride in ushorts (144 B rows)
    constexpr int SB   = 68;            // Bs stride in words   (272 B rows)

    __shared__ unsigned short As_h[BM * SA];
    __shared__ unsigned short As_l[BM * SA];
    __shared__ unsigned int   Bs[64 * SB];

    const int t  = threadIdx.x;
    const int o0 = blockIdx.x * BM;
    const int n0 = blockIdx.y * 64;
    const int z  = blockIdx.z;
    const int b  = z & 1;
    const int ks = z >> 1;

    const float* Ab = A + (size_t)o0 * KDIM + ks * KLEN;
    const float* Bb = Bmat + ((size_t)b * KDIM + (size_t)ks * KLEN) * TOK + n0;
    float*       Cb = C + ((size_t)z * M + o0) * TOK + n0;

    // staging maps
    const int ak4 = (t & 15) * 4;   // A k-quad
    const int am  = t >> 4;         // A row base (step 16 over p)
    const int btt = t & 63;         // B token (n)
    const int bc4 = (t >> 6) * 4;   // B k-quad base (step 16 over p)

    float4 pa[AP];
    float  pb[16];

#define LOAD_TILE(KT) do {                                                    \
        const float* ap_ = Ab + (KT) * 64 + ak4;                              \
        _Pragma("unroll")                                                     \
        for (int p = 0; p < AP; ++p)                                          \
            pa[p] = *(const float4*)(ap_ + (size_t)(am + 16 * p) * KDIM);     \
        const float* bp_ = Bb + (size_t)(KT) * 64 * TOK + btt;                \
        _Pragma("unroll")                                                     \
        for (int p = 0; p < 4; ++p)                                           \
            _Pragma("unroll")                                                 \
            for (int j = 0; j < 4; ++j)                                       \
                pb[p * 4 + j] = bp_[(size_t)(bc4 + p * 16 + j) * TOK];        \
    } while (0)

#define STORE_TILE() do {                                                     \
        _Pragma("unroll")                                                     \
        for (int p = 0; p < AP; ++p) {                                        \
            const int m_ = am + 16 * p;                                       \
            const float4 v_ = pa[p];                                          \
            const unsigned short h0 = f2bf(v_.x), h1 = f2bf(v_.y),            \
                                 h2 = f2bf(v_.z), h3 = f2bf(v_.w);            \
            const unsigned short l0 = f2bf(v_.x - bf2f(h0)),                  \
                                 l1 = f2bf(v_.y - bf2f(h1)),                  \
                                 l2 = f2bf(v_.z - bf2f(h2)),                  \
                                 l3 = f2bf(v_.w - bf2f(h3));                  \
            *(ushort4*)&As_h[(size_t)m_ * SA + ak4] =                         \
                make_ushort4(h0, h1, h2, h3);                                 \
            *(ushort4*)&As_l[(size_t)m_ * SA + ak4] =                         \
                make_ushort4(l0, l1, l2, l3);                                 \
        }                                                                     \
        _Pragma("unroll")                                                     \
        for (int p = 0; p < 4; ++p) {                                         \
            unsigned int wv0, wv1, wv2, wv3;                                  \
            {                                                                 \
                const float x0 = pb[p * 4 + 0], x1 = pb[p * 4 + 1],           \
                            x2 = pb[p * 4 + 2], x3 = pb[p * 4 + 3];           \
                const unsigned short a0 = f2bf(x0), a1 = f2bf(x1),            \
                                     a2 = f2bf(x2), a3 = f2bf(x3);            \
                wv0 = (unsigned int)a0 |                                      \
                      ((unsigned int)f2bf(x0 - bf2f(a0)) << 16);              \
                wv1 = (unsigned int)a1 |                                      \
                      ((unsigned int)f2bf(x1 - bf2f(a1)) << 16);              \
                wv2 = (unsigned int)a2 |                                      \
                      ((unsigned int)f2bf(x2 - bf2f(a2)) << 16);              \
                wv3 = (unsigned int)a3 |                                      \
                      ((unsigned int)f2bf(x3 - bf2f(a3)) << 16);              \
            }                                                                 \
            *(uint4*)&Bs[(size_t)btt * SB + bc4 + p * 16] =                   \
                make_uint4(wv0, wv1, wv2, wv3);                               \
        }                                                                     \
    } while (0)

    // wave decomposition: 2 m-waves x 2 n-waves; wave tile (BM/2) x 32
    const int wid  = t >> 6;
    const int wm   = wid & 1;
    const int wn   = wid >> 1;
    const int lane = t & 63;
    const int lr   = lane & 15;   // frag row (A) / col (B,D)
    const int lg   = lane >> 4;   // k-chunk group / D row-quad

    const int mwb = wm * (BM / 2);
    const int nwb = wn * 32;

    f32x4 acc[MF][2];
#pragma unroll
    for (int mi = 0; mi < MF; ++mi)
#pragma unroll
        for (int ni = 0; ni < 2; ++ni)
            acc[mi][ni] = (f32x4){0.f, 0.f, 0.f, 0.f};

    LOAD_TILE(0);
    STORE_TILE();
    __syncthreads();

#pragma unroll
    for (int kt = 0; kt < NT; ++kt) {
        if (kt + 1 < NT) LOAD_TILE(kt + 1);   // prefetch next tile to regs

#pragma unroll
        for (int ksp = 0; ksp < 2; ++ksp) {   // two K=32 steps per tile
            const int kb = ksp * 32 + lg * 8; // elem (ushort/word) offset

            short8_t ah[MF], al[MF];
#pragma unroll
            for (int mi = 0; mi < MF; ++mi) {
                const int m_ = mwb + mi * 16 + lr;
                ah[mi] = *(const short8_t*)&As_h[(size_t)m_ * SA + kb];
                al[mi] = *(const short8_t*)&As_l[(size_t)m_ * SA + kb];
            }

            short8_t bh[2], bl[2];
#pragma unroll
            for (int ni = 0; ni < 2; ++ni) {
                const unsigned int* wp =
                    &Bs[(size_t)(nwb + ni * 16 + lr) * SB + kb];
                const uint4 w0 = *(const uint4*)wp;
                const uint4 w1 = *(const uint4*)(wp + 4);
                short8_t h_, l_;
                h_[0] = (short)(w0.x & 0xffffu); l_[0] = (short)(w0.x >> 16);
                h_[1] = (short)(w0.y & 0xffffu); l_[1] = (short)(w0.y >> 16);
                h_[2] = (short)(w0.z & 0xffffu); l_[2] = (short)(w0.z >> 16);
                h_[3] = (short)(w0.w & 0xffffu); l_[3] = (short)(w0.w >> 16);
                h_[4] = (short)(w1.x & 0xffffu); l_[4] = (short)(w1.x >> 16);
                h_[5] = (short)(w1.y & 0xffffu); l_[5] = (short)(w1.y >> 16);
                h_[6] = (short)(w1.z & 0xffffu); l_[6] = (short)(w1.z >> 16);
                h_[7] = (short)(w1.w & 0xffffu); l_[7] = (short)(w1.w >> 16);
                bh[ni] = h_; bl[ni] = l_;
            }

#pragma unroll
            for (int mi = 0; mi < MF; ++mi)
#pragma unroll
                for (int ni = 0; ni < 2; ++ni) {
                    acc[mi][ni] = __builtin_amdgcn_mfma_f32_16x16x32_bf16(
                        ah[mi], bh[ni], acc[mi][ni], 0, 0, 0);
                    acc[mi][ni] = __builtin_amdgcn_mfma_f32_16x16x32_bf16(
                        al[mi], bh[ni], acc[mi][ni], 0, 0, 0);
                    acc[mi][ni] = __builtin_amdgcn_mfma_f32_16x16x32_bf16(
                        ah[mi], bl[ni], acc[mi][ni], 0, 0, 0);
                }
        }

        if (kt + 1 < NT) {
            __syncthreads();
            STORE_TILE();
            __syncthreads();
        }
    }

    // epilogue: D frag -> global (lanes 0..15 of each quad write one row)
#pragma unroll
    for (int mi = 0; mi < MF; ++mi)
#pragma unroll
        for (int ni = 0; ni < 2; ++ni)
#pragma unroll
            for (int r = 0; r < 4; ++r) {
                const int row = mwb + mi * 16 + lg * 4 + r;
                const int col = nwb + ni * 16 + lr;
                Cb[(size_t)row * TOK + col] = acc[mi][ni][r];
            }
#undef LOAD_TILE
#undef STORE_TILE
}

// ---------------------------------------------------------------------------
// Fused per-channel attention (sums the 4 qkv K-split parts inline).
// Block = 256 threads handles (b, d0..d0+1): waves = (dl, g-half).
// bias[h,g] = tab[r(h)-r(g)+30], r(h)=(h>>4)+(h&15): 61 distinct values,
// replicated into brow[31][258] (2-bank step, conflict-free float2 reads).
// Scores bounded (~1.1) -> no max-subtraction; g-half partials merge additively.
// ---------------------------------------------------------------------------
__global__ __launch_bounds__(256)
void attn_f32(const float* __restrict__ qkvp, const float* __restrict__ qkv_b,
              const float* __restrict__ rpb, float* __restrict__ aout)
{
    __shared__ float ks_[2][TOK];      // k * scale * log2e (incl. qkv bias)
    __shared__ float vs_[2][TOK];      // v (incl. qkv bias)
    __shared__ float tab2[64];         // rpb gathered, * log2e
    __shared__ float brow[31][258];    // bias rows, stride 258 (2-bank step)
    __shared__ float lpart[2][TOK];
    __shared__ float apart[2][TOK];

    const int t  = threadIdx.x;
    const int b  = blockIdx.y;
    const int d0 = blockIdx.x * 2;
    const float* q0 = qkvp + (size_t)b * (1536 * TOK);

    // phase 0: bias table (61 values)
    if (t < 61) {
        const int rel = t - 30;
        tab2[t] = rpb[rel < 0 ? rel + 961 : rel] * LOG2E;
    }
    // phase 1: stage k and v for the 2 channels (sum 4 K-split parts + bias)
    {
        const int sel = t >> 7;          // 0: k, 1: v
        const int row = (t >> 6) & 1;    // dl
        const int g4  = (t & 63) * 4;
        const int o   = (sel ? 1024 : 512) + d0 + row;
        const float* p = q0 + (size_t)o * TOK + g4;
        const float bb = qkv_b[o];
        float4 v = make_float4(bb, bb, bb, bb);
#pragma unroll
        for (int pp = 0; pp < QPARTS; ++pp) {
            const float4 x = *(const float4*)(p + (size_t)pp * QPSTRIDE);
            v.x += x.x; v.y += x.y; v.z += x.z; v.w += x.w;
        }
        if (sel == 0) {
            const float s = SCALE * LOG2E;
            v.x *= s; v.y *= s; v.z *= s; v.w *= s;
            *(float4*)&ks_[row][g4] = v;
        } else {
            *(float4*)&vs_[row][g4] = v;
        }
    }
    __syncthreads();
    // phase 2: replicate bias into 31 rows x 256 g
    {
        const int rg = ((t >> 4) & 15) + (t & 15);
#pragma unroll 1
        for (int it = 0; it < 31; ++it)
            brow[it][t] = tab2[it - rg + 30];
    }
    __syncthreads();

    // phase 3: main loop
    const int w   = t >> 6;
    const int dl  = w & 1;
    const int gh  = w >> 1;
    const int hl  = t & 63;
    const int qi  = ((hl & 15) << 2) | (hl >> 4);  // bit-swizzled h-quad index
    const int h0  = qi * 4;
    const int rh0 = (qi >> 2) + 4 * (qi & 3);      // r(h0); r(h0+r)=rh0+r

    float q[4];
    {
        const float* p = q0 + (size_t)(d0 + dl) * TOK + h0;
        const float bb = qkv_b[d0 + dl];
        q[0] = bb; q[1] = bb; q[2] = bb; q[3] = bb;
#pragma unroll
        for (int pp = 0; pp < QPARTS; ++pp) {
            const float4 x = *(const float4*)(p + (size_t)pp * QPSTRIDE);
            q[0] += x.x; q[1] += x.y; q[2] += x.z; q[3] += x.w;
        }
    }

    float l[4]  = {0.f, 0.f, 0.f, 0.f};
    float am[4] = {0.f, 0.f, 0.f, 0.f};

    const int pbeg = gh * 128;
#pragma unroll 2
    for (int p = pbeg; p < pbeg + 128; p += 4) {
        const float4 k4 = *(const float4*)&ks_[dl][p];   // wave-uniform (bcast)
        const float4 v4 = *(const float4*)&vs_[dl][p];
#pragma unroll
        for (int r = 0; r < 4; ++r) {
            const float2 b01 = *(const float2*)&brow[rh0 + r][p];
            const float2 b23 = *(const float2*)&brow[rh0 + r][p + 2];
            float e;
            e = EXP2(fmaf(q[r], k4.x, b01.x)); l[r] += e; am[r] = fmaf(e, v4.x, am[r]);
            e = EXP2(fmaf(q[r], k4.y, b01.y)); l[r] += e; am[r] = fmaf(e, v4.y, am[r]);
            e = EXP2(fmaf(q[r], k4.z, b23.x)); l[r] += e; am[r] = fmaf(e, v4.z, am[r]);
            e = EXP2(fmaf(q[r], k4.w, b23.y)); l[r] += e; am[r] = fmaf(e, v4.w, am[r]);
        }
    }

    // phase 4: merge g-halves, normalize, store
    if (gh == 1) {
        *(float4*)&lpart[dl][h0] = make_float4(l[0], l[1], l[2], l[3]);
        *(float4*)&apart[dl][h0] = make_float4(am[0], am[1], am[2], am[3]);
    }
    __syncthreads();
    if (gh == 0) {
        const float4 lo = *(const float4*)&lpart[dl][h0];
        const float4 ao = *(const float4*)&apart[dl][h0];
        float4 o4;
        o4.x = (am[0] + ao.x) / (l[0] + lo.x);
        o4.y = (am[1] + ao.y) / (l[1] + lo.y);
        o4.z = (am[2] + ao.z) / (l[2] + lo.z);
        o4.w = (am[3] + ao.w) / (l[3] + lo.w);
        *(float4*)(aout + ((size_t)b * 512 + d0 + dl) * TOK + h0) = o4;
    }
}

// ---------------------------------------------------------------------------
// Sum the 4 proj K-split parts + proj bias -> final output [2][512][256]
// ---------------------------------------------------------------------------
__global__ __launch_bounds__(256)
void combine_f32(const float* __restrict__ pp, const float* __restrict__ pb,
                 float* __restrict__ out)
{
    const int gid  = blockIdx.x * 256 + threadIdx.x;
    const int flat = gid * 4;
    const int o = (flat >> 8) & 511;
    float4 a = make_float4(pb[o], pb[o], pb[o], pb[o]);
#pragma unroll
    for (int p = 0; p < PPARTS; ++p) {
        const float4 x = *(const float4*)(pp + (size_t)p * PPSTRIDE + flat);
        a.x += x.x; a.y += x.y; a.z += x.z; a.w += x.w;
    }
    *(float4*)(out + flat) = a;
}

// ---------------------------------------------------------------------------
extern "C" void kernel_launch(void* const* d_in, const int* in_sizes, int n_in,
                              void* d_out, int out_size, void* d_ws, size_t ws_size,
                              hipStream_t stream)
{
    const float* x      = (const float*)d_in[0];   // [2][512][256]
    const float* qkv_w  = (const float*)d_in[1];   // [1536][512]
    const float* qkv_b  = (const float*)d_in[2];   // [1536]
    const float* proj_w = (const float*)d_in[3];   // [512][512]
    const float* proj_b = (const float*)d_in[4];   // [512]
    const float* rpb    = (const float*)d_in[5];   // [961]
    float* out = (float*)d_out;                    // [2][512][256]
    float* ws  = (float*)d_ws;

    float* qkvp  = ws;                 // 8 * 393216
    float* aout  = ws + 3145728;       // 262144
    float* projp = ws + 3407872;       // 8 * 131072

    // qkv = qkv_w @ x: M=1536, BM=64, Ksplit=4 -> grid (24,4,8) = 768 blocks
    gemm_mfma<64, 4><<<dim3(24, 4, 8), 256, 0, stream>>>(qkv_w, x, qkvp, 1536);

    // fused attention: grid (d-pairs=256, b=2), sums 4 qkv parts inline
    attn_f32<<<dim3(256, 2), 256, 0, stream>>>(qkvp, qkv_b, rpb, aout);

    // proj = proj_w @ aout: M=512, BM=64, Ksplit=4 -> grid (8,4,8) = 256 blocks
    gemm_mfma<64, 4><<<dim3(8, 4, 8), 256, 0, stream>>>(proj_w, aout, projp, 512);

    // sum 4 parts + bias
    combine_f32<<<dim3(256), 256, 0, stream>>>(projp, proj_b, out);
}